// Round 13
// baseline (316.652 us; speedup 1.0000x reference)
//
#include <hip/hip_runtime.h>
#include <hip/hip_bf16.h>

// sqllm 4-bit GEMM: out[m,n] = sum_k A[m,k] * lut[n, nibble(qweight[k/8,n], k%8)]
// M=8192, N=4096, K=4096. PRE path: A->bf16, W dequant once into ws.
// GEMM: 256x128 tile, 4 waves, 3-slot LDS rings (72 KB) -> 2 blocks/CU.
// Mechanism (m114): two co-resident independent blocks drift and overlap
// each other's {MFMA} vs {ds_read/stage} phases - breaking the 1-block
// barrier convoy that pinned 7 schedule variants at 45% MfmaUtil.
// All staging is pure global_load_lds (single vmcnt class - R11/R12's
// mixed-class ledger was the correctness bug).

typedef __attribute__((ext_vector_type(4))) float  f32x4;
typedef __attribute__((ext_vector_type(4))) int    i32x4;
typedef __attribute__((ext_vector_type(8))) short  bf16x8;

__device__ __forceinline__ unsigned short f2bf(float f) {
    __hip_bfloat16 h = __float2bfloat16(f);
    return __builtin_bit_cast(unsigned short, h);
}

__device__ __forceinline__ void gload16(const unsigned short* g, unsigned short* l) {
    __builtin_amdgcn_global_load_lds(
        (const __attribute__((address_space(1))) unsigned int*)g,
        (__attribute__((address_space(3))) unsigned int*)l, 16, 0, 0);
}

// ---------------- prepass kernels ----------------

__global__ void convA_kernel(const float* __restrict__ in, unsigned short* __restrict__ o, long n8) {
    long i = (long)blockIdx.x * blockDim.x + threadIdx.x;
    long stride = (long)gridDim.x * blockDim.x;
    const f32x4* in4 = reinterpret_cast<const f32x4*>(in);
    bf16x8* o8 = reinterpret_cast<bf16x8*>(o);
    for (; i < n8; i += stride) {
        f32x4 a = in4[2 * i];
        f32x4 b = in4[2 * i + 1];
        bf16x8 e;
#pragma unroll
        for (int x = 0; x < 4; ++x) {
            e[x]     = (short)f2bf(a[x]);
            e[4 + x] = (short)f2bf(b[x]);
        }
        o8[i] = e;
    }
}

// Wb layout: [K/8][N][8] bf16 — prepass write and GEMM staging both coalesced.
__global__ void dequantW_kernel(const int* __restrict__ Q, const float* __restrict__ lut,
                                unsigned short* __restrict__ Wb, int N, long total) {
    long i = (long)blockIdx.x * blockDim.x + threadIdx.x;
    if (i >= total) return;
    unsigned int v = (unsigned int)Q[i];
    int n = (int)(i % N);
    const float* lp = lut + (long)n * 16;
    bf16x8 w;
#pragma unroll
    for (int p = 0; p < 8; ++p)
        w[p] = (short)f2bf(lp[(v >> (4 * p)) & 15]);
    reinterpret_cast<bf16x8*>(Wb)[i] = w;
}

// ---------------- 256x128 GEMM, 2 blocks/CU ----------------
// 4 waves (2M x 2N), per-wave 128x64 out (acc[8][4]). LDS: 3-slot rings of
// 32-k halves: A [256m][4kc-swz][8] 16KB/slot, B [4kc][128n][8] 8KB/slot.
// Phase h: stage half h+2 -> slot stg; ds_read slot cur (compiler lgkm);
// 32 MFMA (setprio); vmcnt(6) (6 gloads/phase -> forces stage(h+1)); barrier.
// WAR: slot reuse distance 3; all reads of a slot lgkm-complete before their
// wave's MFMA, hence before the barrier preceding the overwrite.

__global__ __launch_bounds__(256, 2)
void gemm2b(const unsigned short* __restrict__ Abf, const unsigned short* __restrict__ Wb,
            float* __restrict__ out, int M, int N, int K) {
    __shared__ __align__(16) unsigned short sA[3 * 8192];  // 48 KB
    __shared__ __align__(16) unsigned short sB[3 * 4096];  // 24 KB

    const int tid  = threadIdx.x;
    const int lane = tid & 63;
    const int wid  = tid >> 6;   // 0..3
    const int wr   = wid >> 1;   // 0..1 (128-row half)
    const int wc   = wid & 1;    // 0..1 (64-col half)
    const int r15  = lane & 15;
    const int hi   = lane >> 4;

    // XCD-aware bijective swizzle (nwg % 8 == 0 here)
    const int NBN = N / 128;
    int nwg = gridDim.x, orig = blockIdx.x;
    int wg = ((nwg & 7) == 0) ? (orig & 7) * (nwg >> 3) + (orig >> 3) : orig;
    const int m0 = (wg / NBN) * 256, n0 = (wg % NBN) * 128;

    const int NH = K / 32;  // 32-k halves

    // per-lane ds_read bases (ushort elements)
    const int aoff = (wr * 128 + r15) * 32 + ((hi ^ ((r15 >> 1) & 3)) << 3);
    const int boff = hi * 1024 + (wc * 64 + r15) * 8;

    // staging bases (pure gload_lds; 6 per thread per half: 4 A + 2 B)
    const int am  = tid >> 2, akc = tid & 3;
    const int akcs = (akc ^ ((am >> 1) & 3)) << 3;
    const unsigned short* baseA = Abf + (size_t)(m0 + am) * K + akcs;
    const size_t ajump = (size_t)64 * K;       // +64 m-rows per j
    const int bn = tid & 127, bk0 = tid >> 7;  // 0..1
    const unsigned short* baseB0 = Wb + ((size_t)bk0 * N + n0 + bn) * 8;
    const unsigned short* baseB1 = Wb + ((size_t)(bk0 + 2) * N + n0 + bn) * 8;
    const size_t bstride = (size_t)32 * N;     // per-half advance (ushorts)
    unsigned short* const dA = sA + wid * 512;
    unsigned short* const dB = sB + wid * 512;

    auto stage = [&](int S, int slot) {
        const unsigned short* a = baseA + (size_t)S * 32;
        unsigned short* da = dA + slot * 8192;
#pragma unroll
        for (int j = 0; j < 4; ++j)
            gload16(a + j * ajump, da + j * 2048);
        gload16(baseB0 + S * bstride, dB + slot * 4096);
        gload16(baseB1 + S * bstride, dB + slot * 4096 + 2048);
    };

    f32x4 acc[8][4] = {};

    // prologue: stage halves 0,1 (12 gloads); vmcnt(6) -> half 0 landed
    stage(0, 0);
    stage(1, 1);
    asm volatile("s_waitcnt vmcnt(6)" ::: "memory");
    __builtin_amdgcn_s_barrier();

    int cur = 0, stg = 2;
    for (int h = 0; h < NH; ++h) {
        int S = h + 2; if (S >= NH) S -= NH;  // tail: dummy wrap keeps ledger uniform
        stage(S, stg);

        const unsigned short* SA = sA + cur * 8192;
        const unsigned short* SB = sB + cur * 4096;
        bf16x8 bv[4], av[8];
#pragma unroll
        for (int nf = 0; nf < 4; ++nf)
            bv[nf] = *(const bf16x8*)(SB + boff + nf * 128);
#pragma unroll
        for (int mf = 0; mf < 8; ++mf)
            av[mf] = *(const bf16x8*)(SA + aoff + mf * 512);

        __builtin_amdgcn_s_setprio(1);
#pragma unroll
        for (int mf = 0; mf < 8; ++mf)
#pragma unroll
            for (int nf = 0; nf < 4; ++nf)
                acc[mf][nf] = __builtin_amdgcn_mfma_f32_16x16x32_bf16(
                    av[mf], bv[nf], acc[mf][nf], 0, 0, 0);
        __builtin_amdgcn_s_setprio(0);

        asm volatile("s_waitcnt vmcnt(6)" ::: "memory");
        __builtin_amdgcn_s_barrier();
        cur = (cur == 2) ? 0 : cur + 1;
        stg = (stg == 2) ? 0 : stg + 1;
    }

    asm volatile("s_waitcnt vmcnt(0)" ::: "memory");  // drain wrap prefetches

    // epilogue: C/D layout col=lane&15, row=(lane>>4)*4+reg
#pragma unroll
    for (int mf = 0; mf < 8; ++mf) {
        const int mrow = m0 + wr * 128 + mf * 16 + hi * 4;
#pragma unroll
        for (int nf = 0; nf < 4; ++nf) {
            const int ncol = n0 + wc * 64 + nf * 16 + r15;
            float* po = out + (size_t)mrow * N + ncol;
#pragma unroll
            for (int r = 0; r < 4; ++r) po[(size_t)r * N] = acc[mf][nf][r];
        }
    }
}

// ---------------- fallback fused kernel (small ws only) ----------------

#define FBM 128
#define FBN 128
#define FBK 64

__device__ __forceinline__ int fswz(int row, int kb) {
    return row * (FBK * 2) + (kb ^ ((row & 7) << 4));
}

__global__ __launch_bounds__(256, 2)
void sqllm_gemm_fused(const float* __restrict__ A, const int* __restrict__ Q,
                      const float* __restrict__ lut, float* __restrict__ out,
                      int M, int N, int K) {
    __shared__ __align__(16) char sA[FBM * FBK * 2];
    __shared__ __align__(16) char sB[FBN * FBK * 2];
    __shared__ float sLut[FBN * 17];

    const int tid  = threadIdx.x;
    const int lane = tid & 63;
    const int wid  = tid >> 6;
    const int wr   = wid >> 1;
    const int wc   = wid & 1;
    const int n0 = blockIdx.x * FBN;
    const int m0 = blockIdx.y * FBM;

    for (int i = tid; i < FBN * 16; i += 256) {
        int n = i >> 4, c = i & 15;
        sLut[n * 17 + c] = lut[(long)(n0 + n) * 16 + c];
    }
    __syncthreads();

    f32x4 acc[4][4] = {};
    const int nK = K / FBK;
    for (int kk = 0; kk < nK; ++kk) {
        {
            const int r = tid >> 1, h = tid & 1;
            const float* ap = A + (long)(m0 + r) * K + kk * FBK + h * 32;
            f32x4 v[8];
#pragma unroll
            for (int j = 0; j < 8; ++j) v[j] = reinterpret_cast<const f32x4*>(ap)[j];
            const int kr = tid >> 5, nq = (tid & 31) << 2;
            const int* qp = Q + (long)(kk * (FBK / 8) + kr) * N + n0 + nq;
            i32x4 q = *reinterpret_cast<const i32x4*>(qp);
#pragma unroll
            for (int j = 0; j < 4; ++j) {
                bf16x8 e;
#pragma unroll
                for (int x = 0; x < 4; ++x) {
                    e[x]     = (short)f2bf(v[2 * j][x]);
                    e[4 + x] = (short)f2bf(v[2 * j + 1][x]);
                }
                *reinterpret_cast<bf16x8*>(sA + fswz(r, h * 64 + j * 16)) = e;
            }
#pragma unroll
            for (int c = 0; c < 4; ++c) {
                const int n = nq + c;
                const float* lp = sLut + n * 17;
                unsigned int qq = (unsigned int)q[c];
                bf16x8 w;
#pragma unroll
                for (int p = 0; p < 8; ++p)
                    w[p] = (short)f2bf(lp[(qq >> (4 * p)) & 15]);
                *reinterpret_cast<bf16x8*>(sB + fswz(n, kr * 16)) = w;
            }
        }
        __syncthreads();
#pragma unroll
        for (int kh = 0; kh < 2; ++kh) {
            const int kb = kh * 64 + (lane >> 4) * 16;
            bf16x8 af[4], bfv[4];
#pragma unroll
            for (int i = 0; i < 4; ++i) {
                af[i]  = *reinterpret_cast<const bf16x8*>(sA + fswz(wr * 64 + i * 16 + (lane & 15), kb));
                bfv[i] = *reinterpret_cast<const bf16x8*>(sB + fswz(wc * 64 + i * 16 + (lane & 15), kb));
            }
#pragma unroll
            for (int i = 0; i < 4; ++i)
#pragma unroll
                for (int j = 0; j < 4; ++j)
                    acc[i][j] = __builtin_amdgcn_mfma_f32_16x16x32_bf16(af[i], bfv[j], acc[i][j], 0, 0, 0);
        }
        __syncthreads();
    }
    const int col = lane & 15;
    const int r4  = (lane >> 4) * 4;
#pragma unroll
    for (int i = 0; i < 4; ++i) {
        const int mrow = m0 + wr * 64 + i * 16 + r4;
#pragma unroll
        for (int j = 0; j < 4; ++j) {
            const int ncol = n0 + wc * 64 + j * 16 + col;
#pragma unroll
            for (int r = 0; r < 4; ++r)
                out[(long)(mrow + r) * N + ncol] = acc[i][j][r];
        }
    }
}

extern "C" void kernel_launch(void* const* d_in, const int* in_sizes, int n_in,
                              void* d_out, int out_size, void* d_ws, size_t ws_size,
                              hipStream_t stream) {
    const float* A   = (const float*)d_in[0];
    const int*   Q   = (const int*)d_in[1];
    const float* lut = (const float*)d_in[2];
    float* out = (float*)d_out;

    const long szA = in_sizes[0], szQ = in_sizes[1], szL = in_sizes[2];
    const int N = (int)(szL / 16);
    const int K = (int)(szQ * 8 / N);
    const int M = (int)(szA / K);

    const size_t needA = (size_t)M * K * 2;
    const size_t needW = (size_t)K * N * 2;

    const bool shape_ok = (M % 256 == 0) && (N % 128 == 0) && (K % 64 == 0);

    if (shape_ok && ws_size >= needA + needW) {
        unsigned short* Abf = (unsigned short*)d_ws;
        unsigned short* Wb  = (unsigned short*)((char*)d_ws + needA);
        const long n8 = (long)M * K / 8;
        convA_kernel<<<2048, 256, 0, stream>>>(A, Abf, n8);
        const long tq = (long)(K / 8) * N;
        dequantW_kernel<<<(int)((tq + 255) / 256), 256, 0, stream>>>(Q, lut, Wb, N, tq);
        dim3 grid((M / 256) * (N / 128));
        gemm2b<<<grid, 256, 0, stream>>>(Abf, Wb, out, M, N, K);
    } else {
        dim3 grid(N / FBN, M / FBM);
        sqllm_gemm_fused<<<grid, 256, 0, stream>>>(A, Q, lut, out, M, N, K);
    }
}

// Round 14
// 279.428 us; speedup vs baseline: 1.1332x; 1.1332x over previous
//
#include <hip/hip_runtime.h>
#include <hip/hip_bf16.h>

// sqllm 4-bit GEMM: out[m,n] = sum_k A[m,k] * lut[n, nibble(qweight[k/8,n], k%8)]
// M=8192, N=4096, K=4096. PRE path: A->bf16, W dequant once into ws.
// GEMM: 256x256, 8 waves, 4-slot LDS ring, all global_load_lds staging.
// KEY CHANGE vs R10: next-phase fragments are read via inline-asm
// ds_read_b128 ("=v" outputs) BEFORE the MFMA block -> live ranges of the
// two frag buffers overlap -> allocator must use distinct registers ->
// kills the WAR interlock that serialized ds-drain behind the MFMA queue.
// lgkmcnt(0)+sched_barrier(0) after MFMA (rule 18); consumption next phase.

typedef __attribute__((ext_vector_type(4))) float  f32x4;
typedef __attribute__((ext_vector_type(4))) int    i32x4;
typedef __attribute__((ext_vector_type(8))) short  bf16x8;

__device__ __forceinline__ unsigned short f2bf(float f) {
    __hip_bfloat16 h = __float2bfloat16(f);
    return __builtin_bit_cast(unsigned short, h);
}

__device__ __forceinline__ void gload16(const unsigned short* g, unsigned short* l) {
    __builtin_amdgcn_global_load_lds(
        (const __attribute__((address_space(1))) unsigned int*)g,
        (__attribute__((address_space(3))) unsigned int*)l, 16, 0, 0);
}

// ---------------- prepass kernels ----------------

__global__ void convA_kernel(const float* __restrict__ in, unsigned short* __restrict__ o, long n8) {
    long i = (long)blockIdx.x * blockDim.x + threadIdx.x;
    long stride = (long)gridDim.x * blockDim.x;
    const f32x4* in4 = reinterpret_cast<const f32x4*>(in);
    bf16x8* o8 = reinterpret_cast<bf16x8*>(o);
    for (; i < n8; i += stride) {
        f32x4 a = in4[2 * i];
        f32x4 b = in4[2 * i + 1];
        bf16x8 e;
#pragma unroll
        for (int x = 0; x < 4; ++x) {
            e[x]     = (short)f2bf(a[x]);
            e[4 + x] = (short)f2bf(b[x]);
        }
        o8[i] = e;
    }
}

__global__ void dequantW_kernel(const int* __restrict__ Q, const float* __restrict__ lut,
                                unsigned short* __restrict__ Wb, int N, long total) {
    long i = (long)blockIdx.x * blockDim.x + threadIdx.x;
    if (i >= total) return;
    unsigned int v = (unsigned int)Q[i];
    int n = (int)(i % N);
    const float* lp = lut + (long)n * 16;
    bf16x8 w;
#pragma unroll
    for (int p = 0; p < 8; ++p)
        w[p] = (short)f2bf(lp[(v >> (4 * p)) & 15]);
    reinterpret_cast<bf16x8*>(Wb)[i] = w;
}

// ---------------- 256x256 GEMM, asm-ds_read pipelined phases ----------------
// Half H -> slot H&3. Phase H:
//   stage(H+3 -> slot (H+3)&3)  [4 gload_lds]
//   vmcnt(8)   (outstanding stage(H+2):4 + stage(H+3):4 = 8 -> forces H+1)
//   12x asm ds_read_b128 (slot (H+1)&3) -> NA/NB   (distinct regs, no wait)
//   sched_barrier; setprio(1); 32 MFMA on CA/CB; setprio(0)
//   lgkmcnt(0); sched_barrier; s_barrier
// WAR: slot (H+3)&3's last reads were in phase H-2 (lgkm0 + 2 barriers ago).

#define DSR(dst, addr, OFF) \
    asm volatile("ds_read_b128 %0, %1 offset:" #OFF : "=v"(dst) : "v"(addr))

#define LOADFRAGS_ASM(NA, NB, SLOT) do {                                          \
    unsigned ab_ = aByte + (unsigned)(SLOT) * 16384u;                             \
    unsigned bb_ = bByte + (unsigned)(SLOT) * 16384u;                             \
    DSR(NB[0], bb_, 0);    DSR(NB[1], bb_, 256);                                  \
    DSR(NB[2], bb_, 512);  DSR(NB[3], bb_, 768);                                  \
    DSR(NA[0], ab_, 0);    DSR(NA[1], ab_, 1024);                                 \
    DSR(NA[2], ab_, 2048); DSR(NA[3], ab_, 3072);                                 \
    DSR(NA[4], ab_, 4096); DSR(NA[5], ab_, 5120);                                 \
    DSR(NA[6], ab_, 6144); DSR(NA[7], ab_, 7168);                                 \
} while (0)

#define MFMABLOCK(CA, CB)                                                         \
    _Pragma("unroll") for (int mf = 0; mf < 8; ++mf)                              \
        _Pragma("unroll") for (int nf = 0; nf < 4; ++nf)                          \
            acc[mf][nf] = __builtin_amdgcn_mfma_f32_16x16x32_bf16(                \
                CA[mf], CB[nf], acc[mf][nf], 0, 0, 0);

#define PHASE(U, CA, CB, NA, NB) do {                                             \
    int S3 = H + (U) + 3; if (S3 >= NH) S3 -= NH;                                 \
    stage(S3, ((U) + 3) & 3);                                                     \
    asm volatile("s_waitcnt vmcnt(8)" ::: "memory");                              \
    LOADFRAGS_ASM(NA, NB, ((U) + 1) & 3);                                         \
    __builtin_amdgcn_sched_barrier(0);                                            \
    __builtin_amdgcn_s_setprio(1);                                                \
    MFMABLOCK(CA, CB)                                                             \
    __builtin_amdgcn_s_setprio(0);                                                \
    asm volatile("s_waitcnt lgkmcnt(0)" ::: "memory");                            \
    __builtin_amdgcn_sched_barrier(0);                                            \
    __builtin_amdgcn_s_barrier();                                                 \
} while (0)

__global__ __launch_bounds__(512, 2)
void gemm8p(const unsigned short* __restrict__ Abf, const unsigned short* __restrict__ Wb,
            float* __restrict__ out, int M, int N, int K) {
    __shared__ __align__(16) unsigned short sA[4 * 8192];  // 64 KB: 4 slots x 256m x 32k (kc swz)
    __shared__ __align__(16) unsigned short sB[4 * 8192];  // 64 KB: 4 slots x 4kc x 256n x 8

    const int tid  = threadIdx.x;
    const int lane = tid & 63;
    const int wid  = tid >> 6;
    const int wr   = wid >> 2;   // 0..1  (128-row half)
    const int wc   = wid & 3;    // 0..3  (64-col slice)
    const int r15  = lane & 15;
    const int hi   = lane >> 4;

    const int NBN = N / 256;
    int nwg = gridDim.x, orig = blockIdx.x;
    int wg = ((nwg & 7) == 0) ? (orig & 7) * (nwg >> 3) + (orig >> 3) : orig;
    const int m0 = (wg / NBN) * 256, n0 = (wg % NBN) * 256;

    const int NH = K / 32;  // 32-k halves (NH % 4 == 0)

    // per-lane ds_read byte bases (LDS address space)
    const int aoff = (wr * 128 + r15) * 32 + ((hi ^ ((r15 >> 1) & 3)) << 3);
    const int boff = hi * 2048 + (wc * 64 + r15) * 8;
    const unsigned aByte = (unsigned)(unsigned long long)
        ((__attribute__((address_space(3))) unsigned short*)sA + aoff);
    const unsigned bByte = (unsigned)(unsigned long long)
        ((__attribute__((address_space(3))) unsigned short*)sB + boff);

    // staging bases: 2 A + 2 B gload_lds per thread per half
    const int am  = tid >> 2, akc = tid & 3;
    const int akcs = (akc ^ ((am >> 1) & 3)) << 3;
    const unsigned short* baseA0 = Abf + (size_t)(m0 + am) * K + akcs;
    const unsigned short* baseA1 = Abf + (size_t)(m0 + am + 128) * K + akcs;
    const int bkc = tid >> 8, bn = tid & 255;
    const unsigned short* baseB0 = Wb + ((size_t)bkc * N + n0 + bn) * 8;
    const unsigned short* baseB1 = Wb + ((size_t)(bkc + 2) * N + n0 + bn) * 8;
    const size_t bstride = (size_t)32 * N;
    unsigned short* const dA = sA + wid * 512;
    unsigned short* const dB = sB + wid * 512;

    auto stage = [&](int S, int slot) {
        gload16(baseA0 + S * 32, dA + slot * 8192);
        gload16(baseB0 + S * bstride, dB + slot * 8192);
        gload16(baseA1 + S * 32, dA + slot * 8192 + 4096);
        gload16(baseB1 + S * bstride, dB + slot * 8192 + 4096);
    };

    f32x4 acc[8][4] = {};
    bf16x8 avA[8], bvA[4], avB[8], bvB[4];

    // prologue: stage halves 0,1,2 (12 loads); vmcnt(8) forces slot 0; barrier;
    // plain-load frags(0) (compiler inserts its own lgkm wait before first MFMA)
    stage(0, 0);
    stage(1, 1);
    stage(2, 2);
    asm volatile("s_waitcnt vmcnt(8)" ::: "memory");
    __builtin_amdgcn_s_barrier();
#pragma unroll
    for (int nf = 0; nf < 4; ++nf) bvA[nf] = *(const bf16x8*)(sB + boff + nf * 128);
#pragma unroll
    for (int mf = 0; mf < 8; ++mf) avA[mf] = *(const bf16x8*)(sA + aoff + mf * 512);

    for (int H = 0; H < NH; H += 4) {
        PHASE(0, avA, bvA, avB, bvB);
        PHASE(1, avB, bvB, avA, bvA);
        PHASE(2, avA, bvA, avB, bvB);
        PHASE(3, avB, bvB, avA, bvA);
    }

    asm volatile("s_waitcnt vmcnt(0)" ::: "memory");  // drain wrap prefetches

    // epilogue: C/D layout col=lane&15, row=(lane>>4)*4+reg
#pragma unroll
    for (int mf = 0; mf < 8; ++mf) {
        const int mrow = m0 + wr * 128 + mf * 16 + hi * 4;
#pragma unroll
        for (int nf = 0; nf < 4; ++nf) {
            const int ncol = n0 + wc * 64 + nf * 16 + r15;
            float* po = out + (size_t)mrow * N + ncol;
#pragma unroll
            for (int r = 0; r < 4; ++r) po[(size_t)r * N] = acc[mf][nf][r];
        }
    }
}

#undef PHASE
#undef MFMABLOCK
#undef LOADFRAGS_ASM
#undef DSR

// ---------------- fallback fused kernel (small ws only) ----------------

#define FBM 128
#define FBN 128
#define FBK 64

__device__ __forceinline__ int fswz(int row, int kb) {
    return row * (FBK * 2) + (kb ^ ((row & 7) << 4));
}

__global__ __launch_bounds__(256, 2)
void sqllm_gemm_fused(const float* __restrict__ A, const int* __restrict__ Q,
                      const float* __restrict__ lut, float* __restrict__ out,
                      int M, int N, int K) {
    __shared__ __align__(16) char sA[FBM * FBK * 2];
    __shared__ __align__(16) char sB[FBN * FBK * 2];
    __shared__ float sLut[FBN * 17];

    const int tid  = threadIdx.x;
    const int lane = tid & 63;
    const int wid  = tid >> 6;
    const int wr   = wid >> 1;
    const int wc   = wid & 1;
    const int n0 = blockIdx.x * FBN;
    const int m0 = blockIdx.y * FBM;

    for (int i = tid; i < FBN * 16; i += 256) {
        int n = i >> 4, c = i & 15;
        sLut[n * 17 + c] = lut[(long)(n0 + n) * 16 + c];
    }
    __syncthreads();

    f32x4 acc[4][4] = {};
    const int nK = K / FBK;
    for (int kk = 0; kk < nK; ++kk) {
        {
            const int r = tid >> 1, h = tid & 1;
            const float* ap = A + (long)(m0 + r) * K + kk * FBK + h * 32;
            f32x4 v[8];
#pragma unroll
            for (int j = 0; j < 8; ++j) v[j] = reinterpret_cast<const f32x4*>(ap)[j];
            const int kr = tid >> 5, nq = (tid & 31) << 2;
            const int* qp = Q + (long)(kk * (FBK / 8) + kr) * N + n0 + nq;
            i32x4 q = *reinterpret_cast<const i32x4*>(qp);
#pragma unroll
            for (int j = 0; j < 4; ++j) {
                bf16x8 e;
#pragma unroll
                for (int x = 0; x < 4; ++x) {
                    e[x]     = (short)f2bf(v[2 * j][x]);
                    e[4 + x] = (short)f2bf(v[2 * j + 1][x]);
                }
                *reinterpret_cast<bf16x8*>(sA + fswz(r, h * 64 + j * 16)) = e;
            }
#pragma unroll
            for (int c = 0; c < 4; ++c) {
                const int n = nq + c;
                const float* lp = sLut + n * 17;
                unsigned int qq = (unsigned int)q[c];
                bf16x8 w;
#pragma unroll
                for (int p = 0; p < 8; ++p)
                    w[p] = (short)f2bf(lp[(qq >> (4 * p)) & 15]);
                *reinterpret_cast<bf16x8*>(sB + fswz(n, kr * 16)) = w;
            }
        }
        __syncthreads();
#pragma unroll
        for (int kh = 0; kh < 2; ++kh) {
            const int kb = kh * 64 + (lane >> 4) * 16;
            bf16x8 af[4], bfv[4];
#pragma unroll
            for (int i = 0; i < 4; ++i) {
                af[i]  = *reinterpret_cast<const bf16x8*>(sA + fswz(wr * 64 + i * 16 + (lane & 15), kb));
                bfv[i] = *reinterpret_cast<const bf16x8*>(sB + fswz(wc * 64 + i * 16 + (lane & 15), kb));
            }
#pragma unroll
            for (int i = 0; i < 4; ++i)
#pragma unroll
                for (int j = 0; j < 4; ++j)
                    acc[i][j] = __builtin_amdgcn_mfma_f32_16x16x32_bf16(af[i], bfv[j], acc[i][j], 0, 0, 0);
        }
        __syncthreads();
    }
    const int col = lane & 15;
    const int r4  = (lane >> 4) * 4;
#pragma unroll
    for (int i = 0; i < 4; ++i) {
        const int mrow = m0 + wr * 64 + i * 16 + r4;
#pragma unroll
        for (int j = 0; j < 4; ++j) {
            const int ncol = n0 + wc * 64 + j * 16 + col;
#pragma unroll
            for (int r = 0; r < 4; ++r)
                out[(long)(mrow + r) * N + ncol] = acc[i][j][r];
        }
    }
}

extern "C" void kernel_launch(void* const* d_in, const int* in_sizes, int n_in,
                              void* d_out, int out_size, void* d_ws, size_t ws_size,
                              hipStream_t stream) {
    const float* A   = (const float*)d_in[0];
    const int*   Q   = (const int*)d_in[1];
    const float* lut = (const float*)d_in[2];
    float* out = (float*)d_out;

    const long szA = in_sizes[0], szQ = in_sizes[1], szL = in_sizes[2];
    const int N = (int)(szL / 16);
    const int K = (int)(szQ * 8 / N);
    const int M = (int)(szA / K);

    const size_t needA = (size_t)M * K * 2;
    const size_t needW = (size_t)K * N * 2;

    const bool shape_ok = (M % 256 == 0) && (N % 256 == 0) && (K % 128 == 0);

    if (shape_ok && ws_size >= needA + needW) {
        unsigned short* Abf = (unsigned short*)d_ws;
        unsigned short* Wb  = (unsigned short*)((char*)d_ws + needA);
        const long n8 = (long)M * K / 8;
        convA_kernel<<<2048, 256, 0, stream>>>(A, Abf, n8);
        const long tq = (long)(K / 8) * N;
        dequantW_kernel<<<(int)((tq + 255) / 256), 256, 0, stream>>>(Q, lut, Wb, N, tq);
        dim3 grid((M / 256) * (N / 256));
        gemm8p<<<grid, 512, 0, stream>>>(Abf, Wb, out, M, N, K);
    } else {
        dim3 grid(N / FBN, M / FBM);
        sqllm_gemm_fused<<<grid, 256, 0, stream>>>(A, Q, lut, out, M, N, K);
    }
}